// Round 7
// baseline (200.983 us; speedup 1.0000x reference)
//
#include <hip/hip_runtime.h>
#include <hip/hip_bf16.h>

#define NN 50000
#define NE 600000

typedef __attribute__((ext_vector_type(4))) float f32x4;
typedef __attribute__((ext_vector_type(8))) __bf16 bf16x8;

__device__ __forceinline__ unsigned pack2bf16(float x, float y) {
  __bf16 lo = (__bf16)x, hi = (__bf16)y;
  unsigned short ul = __builtin_bit_cast(unsigned short, lo);
  unsigned short uh = __builtin_bit_cast(unsigned short, hi);
  return (unsigned)ul | ((unsigned)uh << 16);
}

// ---------- CSR build ----------
__global__ void k_zero(int* __restrict__ degi) {
  int i = blockIdx.x * 256 + threadIdx.x;
  if (i < NN) degi[i] = 0;
}

__global__ void k_count(const int* __restrict__ dstv, int* __restrict__ degi) {
  int e = blockIdx.x * 256 + threadIdx.x;
  if (e < NE) atomicAdd(&degi[dstv[e]], 1);
}

// block-inclusive scan of PADDED degrees (rows padded to multiple of 8)
__global__ __launch_bounds__(256) void k_scan1(const int* __restrict__ degi, int* __restrict__ rp,
                                               int* __restrict__ bsum) {
  __shared__ int s[256];
  int gid = blockIdx.x * 256 + threadIdx.x;
  int d = (gid < NN) ? degi[gid] : 0;
  int pd = (d + 7) & ~7;
  s[threadIdx.x] = pd;
  __syncthreads();
  int acc = pd;
  for (int off = 1; off < 256; off <<= 1) {
    int add = (threadIdx.x >= off) ? s[threadIdx.x - off] : 0;
    __syncthreads();
    acc += add;
    s[threadIdx.x] = acc;
    __syncthreads();
  }
  if (gid < NN) rp[gid + 1] = acc;
  if (threadIdx.x == 255) bsum[blockIdx.x] = acc;
}

// finalize rp/cur/dinv + pre-zero pad slots; each block re-scans bsum locally (196 entries)
__global__ __launch_bounds__(256) void k_scan3z(int* __restrict__ rp, const int* __restrict__ bsum,
                                                const int* __restrict__ degi, int* __restrict__ cur,
                                                float* __restrict__ dinv, int2* __restrict__ edg,
                                                int nb) {
  __shared__ int s[256];
  int tid = threadIdx.x, bid = blockIdx.x;
  int v = (tid < nb) ? bsum[tid] : 0;
  s[tid] = v;
  __syncthreads();
  int acc = v;
  for (int off = 1; off < 256; off <<= 1) {
    int add = (tid >= off) ? s[tid - off] : 0;
    __syncthreads();
    acc += add;
    s[tid] = acc;
    __syncthreads();
  }
  int blkoff = (bid > 0) ? s[bid - 1] : 0;
  int gid = bid * 256 + tid;
  if (gid < NN) {
    int d = degi[gid];
    int pd = (d + 7) & ~7;
    int incl = rp[gid + 1] + blkoff;  // inclusive padded prefix through gid
    rp[gid + 1] = incl;
    int start = incl - pd;
    cur[gid] = start;
    dinv[gid] = rsqrtf((float)(d + 1));  // +1 self-loop; always > 0
    for (int j = start + d; j < incl; j++) edg[j] = make_int2(0, 0);  // pad slots, disjoint from fill
  }
  if (gid == 0) rp[0] = 0;
}

__global__ void k_fill(const int* __restrict__ srcv, const int* __restrict__ dstv,
                       int* __restrict__ cur, int2* __restrict__ edg, const float* __restrict__ dinv) {
  int e = blockIdx.x * 256 + threadIdx.x;
  if (e < NE) {
    int s = srcv[e], d = dstv[e];
    int p = atomicAdd(&cur[d], 1);
    edg[p] = make_int2(s, __float_as_int(dinv[s] * dinv[d]));
  }
}

// ---------- conflict-free W^T staging: wt[j][k] = W[k][j] ----------
__device__ __forceinline__ void stage_wt(const float* __restrict__ W, __bf16 (*wt)[136], int tid) {
  int j = tid & 127;
  int hi = tid >> 7;  // 0 or 1
#pragma unroll 4
  for (int it = 0; it < 32; ++it) {
    int kp = ((it << 1) + hi + (j >> 3)) & 63;
    float w0 = W[(kp * 2) * 128 + j];
    float w1 = W[(kp * 2 + 1) * 128 + j];
    *(unsigned*)(&wt[j][kp * 2]) = pack2bf16(w0, w1);
  }
}

// ---------- dense [N,128] @ [128,128], bf16 MFMA ----------
// BR bit0 = add bias, bit1 = relu. IN_BF16: input dtype. DUAL: also write fp32 copy.
template<int BR, bool IN_BF16, bool DUAL>
__global__ __launch_bounds__(256) void k_mm128(const void* __restrict__ Xv, const float* __restrict__ W,
                                               const float* __restrict__ bias, __bf16* __restrict__ Y,
                                               float* __restrict__ Yf, int nrows) {
  __shared__ __bf16 wt[128][136];  // wt[j][k] = W[k][j]
  int tid = threadIdx.x;
  stage_wt(W, wt, tid);
  __syncthreads();
  int lane = tid & 63;
  int strip = blockIdx.x * 4 + (tid >> 6);
  if (strip * 16 >= nrows) return;
  int r16 = lane & 15, g = lane >> 4;
  bf16x8 a[4];
  if constexpr (IN_BF16) {
    const __bf16* xb = (const __bf16*)Xv + (size_t)(strip * 16 + r16) * 128 + g * 8;
#pragma unroll
    for (int ks = 0; ks < 4; ks++) a[ks] = *(const bf16x8*)(xb + ks * 32);
  } else {
    const float* xb = (const float*)Xv + (size_t)(strip * 16 + r16) * 128 + g * 8;
#pragma unroll
    for (int ks = 0; ks < 4; ks++) {
      f32x4 x0 = *(const f32x4*)(xb + ks * 32);
      f32x4 x1 = *(const f32x4*)(xb + ks * 32 + 4);
      bf16x8 v;
      v[0] = (__bf16)x0.x; v[1] = (__bf16)x0.y; v[2] = (__bf16)x0.z; v[3] = (__bf16)x0.w;
      v[4] = (__bf16)x1.x; v[5] = (__bf16)x1.y; v[6] = (__bf16)x1.z; v[7] = (__bf16)x1.w;
      a[ks] = v;
    }
  }
  f32x4 acc[8];
#pragma unroll
  for (int ct = 0; ct < 8; ct++) acc[ct] = (f32x4){0.f, 0.f, 0.f, 0.f};
#pragma unroll
  for (int ct = 0; ct < 8; ct++) {
    const __bf16* wrow = &wt[ct * 16 + r16][g * 8];
#pragma unroll
    for (int ks = 0; ks < 4; ks++) {
      bf16x8 b = *(const bf16x8*)(wrow + ks * 32);
      acc[ct] = __builtin_amdgcn_mfma_f32_16x16x32_bf16(a[ks], b, acc[ct], 0, 0, 0);
    }
  }
  int rbase = strip * 16 + g * 4;
#pragma unroll
  for (int ct = 0; ct < 8; ct++) {
    int col = ct * 16 + r16;
    float bv = (BR & 1) ? bias[col] : 0.f;
#pragma unroll
    for (int i = 0; i < 4; i++) {
      float v = acc[ct][i] + bv;
      if (BR & 2) v = fmaxf(v, 0.f);
      size_t idx = (size_t)(rbase + i) * 128 + col;
      Y[idx] = (__bf16)v;
      if constexpr (DUAL) Yf[idx] = v;
    }
  }
}

// ---------- task heads: bf16 [N,128] @ [128,50] -> y[t][n][c] fp32 ----------
__global__ __launch_bounds__(256) void k_head(const __bf16* __restrict__ H, const float* __restrict__ TW,
                                              const float* __restrict__ TB, float* __restrict__ Y) {
  __shared__ __bf16 wt[64][136];  // wt[o][k] = task_w[o/10][k][o%10], o<50; else 0
  int tid = threadIdx.x;
  for (int i = tid; i < 8192; i += 256) {
    int o = i >> 7, k = i & 127;
    float v = 0.f;
    if (o < 50) v = TW[(o / 10) * 1280 + k * 10 + (o % 10)];
    wt[o][k] = (__bf16)v;
  }
  __syncthreads();
  int lane = tid & 63;
  int strip = blockIdx.x * 4 + (tid >> 6);
  if (strip * 16 >= NN) return;
  int r16 = lane & 15, g = lane >> 4;
  const __bf16* xb = H + (size_t)(strip * 16 + r16) * 128 + g * 8;
  bf16x8 a[4];
#pragma unroll
  for (int ks = 0; ks < 4; ks++) a[ks] = *(const bf16x8*)(xb + ks * 32);
  f32x4 acc[4];
#pragma unroll
  for (int ct = 0; ct < 4; ct++) acc[ct] = (f32x4){0.f, 0.f, 0.f, 0.f};
#pragma unroll
  for (int ct = 0; ct < 4; ct++) {
    const __bf16* wrow = &wt[ct * 16 + r16][g * 8];
#pragma unroll
    for (int ks = 0; ks < 4; ks++) {
      bf16x8 b = *(const bf16x8*)(wrow + ks * 32);
      acc[ct] = __builtin_amdgcn_mfma_f32_16x16x32_bf16(a[ks], b, acc[ct], 0, 0, 0);
    }
  }
  int rbase = strip * 16 + g * 4;
#pragma unroll
  for (int ct = 0; ct < 4; ct++) {
    int o = ct * 16 + r16;
    if (o < 50) {
      int t = o / 10, c = o % 10;
      float tb = TB[o];
#pragma unroll
      for (int i = 0; i < 4; i++) {
        Y[(size_t)t * (NN * 10) + (size_t)(rbase + i) * 10 + c] = acc[ct][i] + tb;
      }
    }
  }
}

// ---------- wide-gather agg helpers ----------
// acc[0..7] += 8 bf16 cols (one uint4) * w
__device__ __forceinline__ void fma8(float* a, uint4 v, float w) {
  unsigned u0 = v.x, u1 = v.y, u2 = v.z, u3 = v.w;
  a[0] = fmaf(__uint_as_float(u0 << 16), w, a[0]);
  a[1] = fmaf(__uint_as_float(u0 & 0xffff0000u), w, a[1]);
  a[2] = fmaf(__uint_as_float(u1 << 16), w, a[2]);
  a[3] = fmaf(__uint_as_float(u1 & 0xffff0000u), w, a[3]);
  a[4] = fmaf(__uint_as_float(u2 << 16), w, a[4]);
  a[5] = fmaf(__uint_as_float(u2 & 0xffff0000u), w, a[5]);
  a[6] = fmaf(__uint_as_float(u3 << 16), w, a[6]);
  a[7] = fmaf(__uint_as_float(u3 & 0xffff0000u), w, a[7]);
}

// one 8-edge step: 1 int4 edge load (per-quarter) + 2 uint4 row loads
__device__ __forceinline__ void step8(const int2* __restrict__ edg, int i, const uint4* __restrict__ T4,
                                      int q, int c8, float* a) {
  int4 ep = ((const int4*)(edg + i))[q];  // edges 2q, 2q+1 of this step
  uint4 r0 = T4[(size_t)ep.x * 16 + c8];
  uint4 r1 = T4[(size_t)ep.z * 16 + c8];
  fma8(a, r0, __int_as_float(ep.y));
  fma8(a, r1, __int_as_float(ep.w));
}

// ---------- CSR pull aggregation: wave = 4 quarter-groups, 4 rows/load-instr, 2 nodes/wave ----------
__global__ __launch_bounds__(256) void k_agg(const unsigned* __restrict__ T, const int* __restrict__ rp,
                                             const int2* __restrict__ edg, const float* __restrict__ dinv,
                                             const float* __restrict__ bias, unsigned* __restrict__ H) {
  int pair = blockIdx.x * 4 + (threadIdx.x >> 6);
  int nA = pair * 2, nB = nA + 1;  // NN even, grid covers exactly
  int lane = threadIdx.x & 63;
  int q = lane >> 4;    // quarter 0..3 (which edge-slot of the step)
  int c8 = lane & 15;   // col block: cols c8*8 .. c8*8+7
  const uint4* T4 = (const uint4*)T;  // row = 16 uint4 (256 B)
  float aA[8] = {0.f, 0.f, 0.f, 0.f, 0.f, 0.f, 0.f, 0.f};
  float aB[8] = {0.f, 0.f, 0.f, 0.f, 0.f, 0.f, 0.f, 0.f};
  int iA = rp[nA], eA = rp[nA + 1];
  int iB = rp[nB], eB = rp[nB + 1];
  while (iA < eA && iB < eB) {  // paired: 6 loads in flight covering 16 edges
    step8(edg, iA, T4, q, c8, aA);
    step8(edg, iB, T4, q, c8, aB);
    iA += 8; iB += 8;
  }
  for (; iA < eA; iA += 8) step8(edg, iA, T4, q, c8, aA);
  for (; iB < eB; iB += 8) step8(edg, iB, T4, q, c8, aB);
  // cross-quarter reduction: lanes {c8, c8+16, c8+32, c8+48} hold same cols
#pragma unroll
  for (int k = 0; k < 8; k++) {
    aA[k] += __shfl_xor(aA[k], 16);
    aA[k] += __shfl_xor(aA[k], 32);
    aB[k] += __shfl_xor(aB[k], 16);
    aB[k] += __shfl_xor(aB[k], 32);
  }
  // self-loop + bias + relu (valid on all lanes; only quarter 0 writes)
  float diA = dinv[nA], diB = dinv[nB];
  fma8(aA, T4[(size_t)nA * 16 + c8], diA * diA);
  fma8(aB, T4[(size_t)nB * 16 + c8], diB * diB);
  f32x4 b0 = ((const f32x4*)bias)[c8 * 2];
  f32x4 b1 = ((const f32x4*)bias)[c8 * 2 + 1];
  float bv[8] = {b0.x, b0.y, b0.z, b0.w, b1.x, b1.y, b1.z, b1.w};
#pragma unroll
  for (int k = 0; k < 8; k++) {
    aA[k] = fmaxf(aA[k] + bv[k], 0.f);
    aB[k] = fmaxf(aB[k] + bv[k], 0.f);
  }
  if (q == 0) {
    uint4 oA, oB;
    oA.x = pack2bf16(aA[0], aA[1]); oA.y = pack2bf16(aA[2], aA[3]);
    oA.z = pack2bf16(aA[4], aA[5]); oA.w = pack2bf16(aA[6], aA[7]);
    oB.x = pack2bf16(aB[0], aB[1]); oB.y = pack2bf16(aB[2], aB[3]);
    oB.z = pack2bf16(aB[4], aB[5]); oB.w = pack2bf16(aB[6], aB[7]);
    ((uint4*)H)[(size_t)nA * 16 + c8] = oA;
    ((uint4*)H)[(size_t)nB * 16 + c8] = oB;
  }
}

extern "C" void kernel_launch(void* const* d_in, const int* in_sizes, int n_in,
                              void* d_out, int out_size, void* d_ws, size_t ws_size,
                              hipStream_t stream) {
  (void)in_sizes; (void)n_in; (void)out_size; (void)ws_size;
  const float* x   = (const float*)d_in[0];
  const int*   ei  = (const int*)d_in[1];
  const float* w1  = (const float*)d_in[2];
  const float* b1  = (const float*)d_in[3];
  const float* w2  = (const float*)d_in[4];
  const float* b2  = (const float*)d_in[5];
  const float* fw1 = (const float*)d_in[6];
  const float* fb1 = (const float*)d_in[7];
  const float* fw2 = (const float*)d_in[8];
  const float* fb2 = (const float*)d_in[9];
  const float* tw  = (const float*)d_in[10];
  const float* tb  = (const float*)d_in[11];
  const int* srcv = ei;
  const int* dstv = ei + NE;

  char* wsb = (char*)d_ws;
  __bf16* bufT = (__bf16*)(wsb + 0);         // 12,800,000 B  [N,128] bf16
  __bf16* hbf  = (__bf16*)(wsb + 12800000);  // 12,800,000 B  [N,128] bf16
  int*    degi = (int*)(wsb + 25600000);     //    200,000 B
  int*    rp   = (int*)(wsb + 25800192);     //    200,004 B
  int*    cur  = (int*)(wsb + 26000640);     //    200,000 B
  int*    bsum = (int*)(wsb + 26200832);     //        784 B
  float*  dinv = (float*)(wsb + 26201856);   //    200,000 B
  int2*   edg  = (int2*)(wsb + 26402048);    //  7,600,000 B (padded rows, <=950k slots)
  // total ~34 MB of 256 MB ws

  float* y_out = (float*)d_out;              // [5,50000,10]
  float* feat  = (float*)d_out + 2500000;    // [50000,128] feature_x fp32

  // --- CSR build: 5 wide kernels ---
  k_zero<<<196, 256, 0, stream>>>(degi);
  k_count<<<(NE + 255) / 256, 256, 0, stream>>>(dstv, degi);
  k_scan1<<<196, 256, 0, stream>>>(degi, rp, bsum);
  k_scan3z<<<196, 256, 0, stream>>>(rp, bsum, degi, cur, dinv, edg, 196);
  k_fill<<<(NE + 255) / 256, 256, 0, stream>>>(srcv, dstv, cur, edg, dinv);

  // --- GCN layer 1 ---
  k_mm128<0, false, false><<<782, 256, 0, stream>>>(x, w1, nullptr, bufT, nullptr, NN);
  k_agg<<<6250, 256, 0, stream>>>((const unsigned*)bufT, rp, edg, dinv, b1, (unsigned*)hbf);
  // --- GCN layer 2 ---
  k_mm128<0, true, false><<<782, 256, 0, stream>>>(hbf, w2, nullptr, bufT, nullptr, NN);
  k_agg<<<6250, 256, 0, stream>>>((const unsigned*)bufT, rp, edg, dinv, b2, (unsigned*)hbf);
  // --- fc1: feature_x (fp32 to d_out, bf16 in-place for fc2) ---
  k_mm128<3, true, true><<<782, 256, 0, stream>>>(hbf, fw1, fb1, hbf, feat, NN);
  // --- fc2 ---
  k_mm128<3, true, false><<<782, 256, 0, stream>>>(hbf, fw2, fb2, bufT, nullptr, NN);
  // --- heads ---
  k_head<<<782, 256, 0, stream>>>(bufT, tw, tb, y_out);
}